// Round 7
// baseline (775.072 us; speedup 1.0000x reference)
//
#include <hip/hip_runtime.h>
#include <math.h>

#define NL 4
#define DMODEL 768
#define DINNER 1536
#define DSTATE 16
#define DCONV 4
#define DTRANK 48
#define BATCH 2
#define SEQLEN 1024
#define MTOK (BATCH*SEQLEN)      // 2048
#define XDIM 80                  // DT_RANK + 2*D_STATE
#define KPAD 64                  // DTRANK padded for MFMA
#define NPAD 96                  // XDIM padded for MFMA (3x32)
#define KS2 16                   // split-K slices for GEMM2
#define NCHUNK 64
#define CLEN 16                  // SEQLEN/NCHUNK
#define CHSTRIDE (BATCH*16*DINNER)   // 49152

typedef __bf16 bf16x8 __attribute__((ext_vector_type(8)));
typedef float f32x4 __attribute__((ext_vector_type(4)));

__device__ __forceinline__ void splitbf(float f, unsigned short& hi, unsigned short& lo) {
    unsigned uh = __float_as_uint(f);
    unsigned rh = uh + (0x7fffu + ((uh >> 16) & 1u));
    unsigned short h = (unsigned short)(rh >> 16);
    float fh = __uint_as_float(((unsigned)h) << 16);
    float r = f - fh;
    unsigned ul = __float_as_uint(r);
    unsigned rl = ul + (0x7fffu + ((ul >> 16) & 1u));
    hi = h;
    lo = (unsigned short)(rl >> 16);
}

__device__ __forceinline__ void splitbf4(float4 v, ushort4& h, ushort4& l) {
    splitbf(v.x, h.x, l.x);
    splitbf(v.y, h.y, l.y);
    splitbf(v.z, h.z, l.z);
    splitbf(v.w, h.w, l.w);
}

__device__ __forceinline__ float bf2f(unsigned short h) {
    return __uint_as_float(((unsigned)h) << 16);
}

__device__ __forceinline__ void gload_lds16(const void* g, void* l) {
    __builtin_amdgcn_global_load_lds(
        (const __attribute__((address_space(1))) unsigned*)g,
        (__attribute__((address_space(3))) unsigned*)l, 16, 0, 0);
}

// ---------------------------------------------------------------------------
// One-shot prep for ALL layers: weight splits (+padding), dt pad-zero (L0),
// x split (L0). grid = (range, NL). Buffers hold all 4 layers.
// ---------------------------------------------------------------------------
#define N_IPW (2 * DINNER * DMODEL / 4)
#define N_OPW (DMODEL * DINNER / 4)
#define N_XPW (NPAD * DINNER / 4)
#define N_DPW (DINNER * KPAD / 4)
#define N_DTP (MTOK * (KPAD - DTRANK) / 4)
#define N_PREP (N_IPW + N_OPW + N_XPW + N_DPW + N_DTP)
#define N_XSPL (MTOK * DMODEL / 4)

__global__ __launch_bounds__(256) void prep_all(
    const float* __restrict__ ipw, const float* __restrict__ opw,
    const float* __restrict__ xpw, const float* __restrict__ dpw,
    const float* __restrict__ x,
    unsigned short* __restrict__ wih, unsigned short* __restrict__ wil,
    unsigned short* __restrict__ woh, unsigned short* __restrict__ wol,
    unsigned short* __restrict__ wxh, unsigned short* __restrict__ wxl,
    unsigned short* __restrict__ wdh, unsigned short* __restrict__ wdl,
    unsigned short* __restrict__ dth, unsigned short* __restrict__ dtl,
    unsigned short* __restrict__ ah, unsigned short* __restrict__ al)
{
    const int L = blockIdx.y;
    int i = blockIdx.x * 256 + threadIdx.x;
    if (i < N_IPW) {
        float4 v = ((const float4*)(ipw + (size_t)L * 2 * DINNER * DMODEL))[i];
        ushort4 h, l;
        splitbf4(v, h, l);
        size_t o = (size_t)L * N_IPW + i;
        ((ushort4*)wih)[o] = h;
        ((ushort4*)wil)[o] = l;
        return;
    }
    i -= N_IPW;
    if (i < N_OPW) {
        float4 v = ((const float4*)(opw + (size_t)L * DMODEL * DINNER))[i];
        ushort4 h, l;
        splitbf4(v, h, l);
        size_t o = (size_t)L * N_OPW + i;
        ((ushort4*)woh)[o] = h;
        ((ushort4*)wol)[o] = l;
        return;
    }
    i -= N_OPW;
    if (i < N_XPW) {
        int e = i * 4;
        int row = e / DINNER, col = e % DINNER;
        ushort4 h = {0, 0, 0, 0}, l = {0, 0, 0, 0};
        if (row < XDIM) {
            float4 v = *(const float4*)(xpw + (size_t)L * XDIM * DINNER + (size_t)row * DINNER + col);
            splitbf4(v, h, l);
        }
        size_t o = (size_t)L * N_XPW + i;
        ((ushort4*)wxh)[o] = h;
        ((ushort4*)wxl)[o] = l;
        return;
    }
    i -= N_XPW;
    if (i < N_DPW) {
        int e = i * 4;
        int row = e >> 6, col = e & 63;
        ushort4 h = {0, 0, 0, 0}, l = {0, 0, 0, 0};
        if (col < DTRANK) {
            float4 v = *(const float4*)(dpw + (size_t)L * DINNER * DTRANK + (size_t)row * DTRANK + col);
            splitbf4(v, h, l);
        }
        size_t o = (size_t)L * N_DPW + i;
        ((ushort4*)wdh)[o] = h;
        ((ushort4*)wdl)[o] = l;
        return;
    }
    i -= N_DPW;
    if (L != 0) return;                 // remaining ranges are layer-0 only
    if (i < N_DTP) {
        int e = i * 4;
        int row = e >> 4, col = DTRANK + (e & 15);
        int o = (row * KPAD + col) / 4;
        ushort4 z = {0, 0, 0, 0};
        ((ushort4*)dth)[o] = z;         // pad cols stay zero across all layers
        ((ushort4*)dtl)[o] = z;
        return;
    }
    i -= N_DTP;
    if (i < N_XSPL) {
        float4 v = ((const float4*)x)[i];
        ushort4 h, l;
        splitbf4(v, h, l);
        ((ushort4*)ah)[i] = h;
        ((ushort4*)al)[i] = l;
    }
}

// ---------------------------------------------------------------------------
// Pre-split 3-pass bf16 MFMA GEMM, XOR-swizzled LDS (bank-conflict-free).
// ---------------------------------------------------------------------------
template<int BM, int BN, int EPI>
__global__ __launch_bounds__(256, 2) void gemm_pre(
    const unsigned short* __restrict__ Ah, const unsigned short* __restrict__ Al, int lda,
    const unsigned short* __restrict__ Wh, const unsigned short* __restrict__ Wl, int ldw,
    float* __restrict__ C, int ldc, int Klen, size_t zstride, int nclip,
    const float* __restrict__ bias)
{
    constexpr int BK = 32;
    constexpr int MT = BM / 32, NT = BN / 32;
    constexpr int ACH = BM * 4;
    constexpr int WCH = BN * 4;
    __shared__ unsigned short sAh[BM * BK];
    __shared__ unsigned short sAl[BM * BK];
    __shared__ unsigned short sWh[BN * BK];
    __shared__ unsigned short sWl[BN * BK];

    const int tid = threadIdx.x;
    const int m0 = blockIdx.y * BM, n0 = blockIdx.x * BN;
    const int kbase = blockIdx.z * Klen;
    C += (size_t)blockIdx.z * zstride;
    const int lane = tid & 63, wave = tid >> 6;
    const int wr = wave >> 1, wc = wave & 1;
    const int wm0 = wr * (BM / 2), wn0 = wc * (BN / 2);
    const int lrow = lane & 15, lq = lane >> 4;

    f32x4 acc[MT][NT];
    #pragma unroll
    for (int mt = 0; mt < MT; mt++)
        #pragma unroll
        for (int nt = 0; nt < NT; nt++) {
            f32x4 z = {0.f, 0.f, 0.f, 0.f};
            acc[mt][nt] = z;
        }

    for (int k0 = kbase; k0 < kbase + Klen; k0 += BK) {
        #pragma unroll
        for (int i = 0; i < (ACH + 255) / 256; i++) {
            int chunk = i * 256 + tid;
            if (ACH % 256 == 0 || chunk < ACH) {
                int r = chunk >> 2, cp = chunk & 3;
                int c = cp ^ ((r >> 1) & 3);
                size_t goff = (size_t)(m0 + r) * lda + k0 + c * 8;
                gload_lds16(Ah + goff, &sAh[chunk * 8]);
                gload_lds16(Al + goff, &sAl[chunk * 8]);
            }
        }
        #pragma unroll
        for (int i = 0; i < (WCH + 255) / 256; i++) {
            int chunk = i * 256 + tid;
            if (WCH % 256 == 0 || chunk < WCH) {
                int r = chunk >> 2, cp = chunk & 3;
                int c = cp ^ ((r >> 1) & 3);
                size_t goff = (size_t)(n0 + r) * ldw + k0 + c * 8;
                gload_lds16(Wh + goff, &sWh[chunk * 8]);
                gload_lds16(Wl + goff, &sWl[chunk * 8]);
            }
        }
        __syncthreads();

        bf16x8 fah[MT], fal[MT], fwh[NT], fwl[NT];
        #pragma unroll
        for (int mt = 0; mt < MT; mt++) {
            int rr = wm0 + mt * 16 + lrow;
            int off = rr * BK + (lq ^ ((rr >> 1) & 3)) * 8;
            fah[mt] = *(const bf16x8*)&sAh[off];
            fal[mt] = *(const bf16x8*)&sAl[off];
        }
        #pragma unroll
        for (int nt = 0; nt < NT; nt++) {
            int rr = wn0 + nt * 16 + lrow;
            int off = rr * BK + (lq ^ ((rr >> 1) & 3)) * 8;
            fwh[nt] = *(const bf16x8*)&sWh[off];
            fwl[nt] = *(const bf16x8*)&sWl[off];
        }
        #pragma unroll
        for (int mt = 0; mt < MT; mt++)
            #pragma unroll
            for (int nt = 0; nt < NT; nt++) {
                acc[mt][nt] = __builtin_amdgcn_mfma_f32_16x16x32_bf16(fah[mt], fwh[nt], acc[mt][nt], 0, 0, 0);
                acc[mt][nt] = __builtin_amdgcn_mfma_f32_16x16x32_bf16(fah[mt], fwl[nt], acc[mt][nt], 0, 0, 0);
                acc[mt][nt] = __builtin_amdgcn_mfma_f32_16x16x32_bf16(fal[mt], fwh[nt], acc[mt][nt], 0, 0, 0);
            }
        __syncthreads();
    }

    // C/D layout: col = lane&15, row = (lane>>4)*4 + reg   [measured m89/m91]
    #pragma unroll
    for (int mt = 0; mt < MT; mt++)
        #pragma unroll
        for (int nt = 0; nt < NT; nt++)
            #pragma unroll
            for (int i = 0; i < 4; i++) {
                int row = m0 + wm0 + mt * 16 + lq * 4 + i;
                int col = n0 + wn0 + nt * 16 + lrow;
                float v = acc[mt][nt][i];
                if (EPI == 2) {
                    float t = v + bias[col];
                    v = fmaxf(t, 0.f) + log1pf(__expf(-fabsf(t)));
                }
                if (col < nclip) C[(size_t)row * ldc + col] = v;
            }
}

// ---------------------------------------------------------------------------
// split-K reduce (4 slices) + optional bf16 hi/lo split for next-layer A
// ---------------------------------------------------------------------------
template<int MODE>
__global__ __launch_bounds__(256) void reduce4(
    const float* __restrict__ part, float* __restrict__ dst,
    unsigned short* __restrict__ hi, unsigned short* __restrict__ lo)
{
    constexpr size_t S = (size_t)MTOK * DMODEL / 4;
    int i = blockIdx.x * 256 + threadIdx.x;
    const float4* p = (const float4*)part;
    float4 a = p[i], b = p[i + S], c = p[i + 2 * S], d = p[i + 3 * S];
    float4 s = {a.x + b.x + c.x + d.x, a.y + b.y + c.y + d.y,
                a.z + b.z + c.z + d.z, a.w + b.w + c.w + d.w};
    if (MODE == 0) {
        ((float4*)dst)[i] = s;
    } else {
        ushort4 h, l;
        splitbf4(s, h, l);
        ((ushort4*)hi)[i] = h;
        ((ushort4*)lo)[i] = l;
    }
}

// ---------------------------------------------------------------------------
// GEMM2 reduce: sum KS2 slices -> xdbl fp32; emit dt cols pre-split.
// ---------------------------------------------------------------------------
__global__ __launch_bounds__(256) void reduce16(
    const float* __restrict__ part, float* __restrict__ xdbl,
    unsigned short* __restrict__ dth, unsigned short* __restrict__ dtl)
{
    constexpr int N4 = MTOK * XDIM / 4;
    constexpr int S4 = MTOK * XDIM / 4;
    int i = blockIdx.x * 256 + threadIdx.x;
    if (i >= N4) return;
    const float4* p = (const float4*)part;
    float4 s = {0.f, 0.f, 0.f, 0.f};
    #pragma unroll
    for (int z = 0; z < KS2; z++) {
        float4 v = p[(size_t)z * S4 + i];
        s.x += v.x; s.y += v.y; s.z += v.z; s.w += v.w;
    }
    ((float4*)xdbl)[i] = s;
    int e = i * 4;
    int col = e % XDIM, row = e / XDIM;
    if (col < DTRANK) {
        ushort4 h, l;
        splitbf4(s, h, l);
        int o = (row * KPAD + col) / 4;
        ((ushort4*)dth)[o] = h;
        ((ushort4*)dtl)[o] = l;
    }
}

// ---------------------------------------------------------------------------
// causal depthwise conv (width 4) + silu -> u emitted as bf16 hi/lo
// ---------------------------------------------------------------------------
__global__ __launch_bounds__(256) void conv_silu_kernel(
    const float* __restrict__ xz, const float* __restrict__ cw,
    const float* __restrict__ cb,
    unsigned short* __restrict__ uh, unsigned short* __restrict__ ul)
{
    int idx = blockIdx.x * 256 + threadIdx.x;   // over MTOK*DINNER
    int d = idx % DINNER;
    int r = idx / DINNER;          // b*SEQLEN + l
    int l = r & (SEQLEN - 1);
    const float* base = xz + (size_t)r * (2 * DINNER) + d;
    float acc = cb[d];
    float w0 = cw[d * 4 + 0], w1 = cw[d * 4 + 1], w2 = cw[d * 4 + 2], w3 = cw[d * 4 + 3];
    if (l >= 3) acc = fmaf(w0, base[-3 * 2 * DINNER], acc);
    if (l >= 2) acc = fmaf(w1, base[-2 * 2 * DINNER], acc);
    if (l >= 1) acc = fmaf(w2, base[-1 * 2 * DINNER], acc);
    acc = fmaf(w3, base[0], acc);
    float uv = acc / (1.f + __expf(-acc));
    unsigned short h, lo_;
    splitbf(uv, h, lo_);
    uh[idx] = h;
    ul[idx] = lo_;
}

// ---------------------------------------------------------------------------
// Chunked parallel scan (3 passes), NCHUNK=64, B/C rows staged in LDS.
// grid = (DINNER/256, NCHUNK, BATCH) so each block shares (b, chunk).
// pass1 emits q + sum(delta); pass2 reconstructs P = exp(Arow*sdl).
// ---------------------------------------------------------------------------
__global__ __launch_bounds__(256, 4) void scan_pass1(
    const float* __restrict__ delta,
    const unsigned short* __restrict__ uh, const unsigned short* __restrict__ ul,
    const float* __restrict__ xdbl, const float* __restrict__ A_log,
    float* __restrict__ qbuf, float* __restrict__ sdlbuf)
{
    __shared__ float sB[CLEN][16];
    const int tid = threadIdx.x;
    const int d = blockIdx.x * 256 + tid;
    const int chunk = blockIdx.y, b = blockIdx.z;
    const int t0 = chunk * CLEN;
    // stage B rows (16 t x 16 n)
    {
        int t = tid >> 4, n = tid & 15;
        sB[t][n] = xdbl[(size_t)(b * SEQLEN + t0 + t) * XDIM + DTRANK + n];
    }
    float Arow[16], q[16];
    #pragma unroll
    for (int n = 0; n < 16; n++) {
        Arow[n] = -__expf(A_log[d * 16 + n]);
        q[n] = 0.f;
    }
    __syncthreads();
    float sdl = 0.f;
    size_t rowbase = (size_t)b * SEQLEN * DINNER + d;
    #pragma unroll 4
    for (int i = 0; i < CLEN; i++) {
        size_t o = rowbase + (size_t)(t0 + i) * DINNER;
        float dl = delta[o];
        float uu = bf2f(uh[o]) + bf2f(ul[o]);
        float du = dl * uu;
        sdl += dl;
        #pragma unroll
        for (int n = 0; n < 16; n++)
            q[n] = fmaf(__expf(dl * Arow[n]), q[n], du * sB[i][n]);
    }
    size_t off = (size_t)((chunk * BATCH + b) * 16) * DINNER + d;
    #pragma unroll
    for (int n = 0; n < 16; n++)
        qbuf[off + (size_t)n * DINNER] = q[n];
    sdlbuf[(size_t)(chunk * BATCH + b) * DINNER + d] = sdl;
}

__global__ __launch_bounds__(256) void scan_pass2(
    const float* __restrict__ qbuf, const float* __restrict__ sdlbuf,
    const float* __restrict__ A_log, float* __restrict__ hinit)
{
    int gid = blockIdx.x * 256 + threadIdx.x;   // BATCH*16*DINNER
    int d = gid % DINNER;
    int n = (gid / DINNER) & 15;
    int b = gid / (16 * DINNER);
    float Arow = -__expf(A_log[d * 16 + n]);
    float h = 0.f;
    #pragma unroll 4
    for (int c = 0; c < NCHUNK; c++) {
        size_t o = (size_t)c * CHSTRIDE + gid;
        hinit[o] = h;
        float p = __expf(Arow * sdlbuf[(size_t)(c * BATCH + b) * DINNER + d]);
        h = fmaf(p, h, qbuf[o]);
    }
}

__global__ __launch_bounds__(256, 4) void scan_pass3(
    const float* __restrict__ delta,
    const unsigned short* __restrict__ uh, const unsigned short* __restrict__ ul,
    const float* __restrict__ xdbl, const float* __restrict__ xz,
    const float* __restrict__ A_log, const float* __restrict__ Dp,
    const float* __restrict__ hinit,
    unsigned short* __restrict__ yh, unsigned short* __restrict__ yl)
{
    __shared__ float sBC[CLEN][32];    // [t][0:16)=B, [16:32)=C
    const int tid = threadIdx.x;
    const int d = blockIdx.x * 256 + tid;
    const int chunk = blockIdx.y, b = blockIdx.z;
    const int t0 = chunk * CLEN;
    #pragma unroll
    for (int idx = tid; idx < CLEN * 32; idx += 256) {
        int t = idx >> 5, j = idx & 31;
        sBC[t][j] = xdbl[(size_t)(b * SEQLEN + t0 + t) * XDIM + DTRANK + j];
    }
    float Arow[16], h[16];
    #pragma unroll
    for (int n = 0; n < 16; n++) Arow[n] = -__expf(A_log[d * 16 + n]);
    size_t hoff = (size_t)chunk * CHSTRIDE + (size_t)(b * 16) * DINNER + d;
    #pragma unroll
    for (int n = 0; n < 16; n++) h[n] = hinit[hoff + (size_t)n * DINNER];
    const float Dpar = Dp[d];
    __syncthreads();
    size_t rowbase = (size_t)b * SEQLEN * DINNER + d;
    #pragma unroll 4
    for (int i = 0; i < CLEN; i++) {
        int t = t0 + i;
        size_t o = rowbase + (size_t)t * DINNER;
        float dl = delta[o];
        float uu = bf2f(uh[o]) + bf2f(ul[o]);
        float du = dl * uu;
        float yt = 0.f;
        #pragma unroll
        for (int n = 0; n < 16; n++) {
            float dA = __expf(dl * Arow[n]);
            h[n] = fmaf(dA, h[n], du * sBC[i][n]);
            yt = fmaf(h[n], sBC[i][16 + n], yt);
        }
        yt = fmaf(uu, Dpar, yt);
        float z = xz[(size_t)(b * SEQLEN + t) * (2 * DINNER) + DINNER + d];
        float sz = z / (1.f + __expf(-z));
        float yv = yt * sz;
        unsigned short hh, ll;
        splitbf(yv, hh, ll);
        yh[o] = hh;
        yl[o] = ll;
    }
}

// ---------------------------------------------------------------------------
extern "C" void kernel_launch(void* const* d_in, const int* in_sizes, int n_in,
                              void* d_out, int out_size, void* d_ws, size_t ws_size,
                              hipStream_t stream) {
    const float* x    = (const float*)d_in[0];
    const float* ipw  = (const float*)d_in[1];
    const float* cw   = (const float*)d_in[2];
    const float* cb   = (const float*)d_in[3];
    const float* xpw  = (const float*)d_in[4];
    const float* dpw  = (const float*)d_in[5];
    const float* dpb  = (const float*)d_in[6];
    const float* alog = (const float*)d_in[7];
    const float* dpar = (const float*)d_in[8];
    const float* opw  = (const float*)d_in[9];
    float* out = (float*)d_out;

    char* ws = (char*)d_ws;
    float* xz    = (float*)ws;            ws += (size_t)MTOK * 2 * DINNER * 4;   // 25.2 MB
    float* delta = (float*)ws;            ws += (size_t)MTOK * DINNER * 4;       // 12.6 MB
    float* xdbl  = (float*)ws;            ws += (size_t)MTOK * XDIM * 4;         // 0.66 MB
    float* qbuf  = (float*)ws;            ws += (size_t)NCHUNK * CHSTRIDE * 4;   // 12.6 MB
    float* hinit = (float*)ws;            ws += (size_t)NCHUNK * CHSTRIDE * 4;   // 12.6 MB
    float* sdlb  = (float*)ws;            ws += (size_t)NCHUNK * BATCH * DINNER * 4; // 0.79 MB
    float* part  = (float*)ws;            ws += (size_t)4 * MTOK * DMODEL * 4;   // 25.2 MB
    unsigned short* ah  = (unsigned short*)ws; ws += (size_t)MTOK * DMODEL * 2;
    unsigned short* al  = (unsigned short*)ws; ws += (size_t)MTOK * DMODEL * 2;
    unsigned short* yh  = (unsigned short*)ws; ws += (size_t)MTOK * DINNER * 2;
    unsigned short* yl  = (unsigned short*)ws; ws += (size_t)MTOK * DINNER * 2;
    unsigned short* uh  = (unsigned short*)ws; ws += (size_t)MTOK * DINNER * 2;
    unsigned short* ul  = (unsigned short*)ws; ws += (size_t)MTOK * DINNER * 2;
    // all-layer weight buffers (x4)
    unsigned short* wih = (unsigned short*)ws; ws += (size_t)NL * 2 * DINNER * DMODEL * 2;
    unsigned short* wil = (unsigned short*)ws; ws += (size_t)NL * 2 * DINNER * DMODEL * 2;
    unsigned short* woh = (unsigned short*)ws; ws += (size_t)NL * DMODEL * DINNER * 2;
    unsigned short* wol = (unsigned short*)ws; ws += (size_t)NL * DMODEL * DINNER * 2;
    unsigned short* wxh = (unsigned short*)ws; ws += (size_t)NL * NPAD * DINNER * 2;
    unsigned short* wxl = (unsigned short*)ws; ws += (size_t)NL * NPAD * DINNER * 2;
    unsigned short* wdh = (unsigned short*)ws; ws += (size_t)NL * DINNER * KPAD * 2;
    unsigned short* wdl = (unsigned short*)ws; ws += (size_t)NL * DINNER * KPAD * 2;
    unsigned short* dth = (unsigned short*)ws; ws += (size_t)MTOK * KPAD * 2;
    unsigned short* dtl = (unsigned short*)ws; ws += (size_t)MTOK * KPAD * 2;

    // one-shot prep: all 4 layers' weight splits + dt pad zero + x split
    prep_all<<<dim3((N_PREP + N_XSPL) / 256, NL), 256, 0, stream>>>(
        ipw, opw, xpw, dpw, x,
        wih, wil, woh, wol, wxh, wxl, wdh, wdl, dth, dtl, ah, al);

    for (int L = 0; L < NL; L++) {
        const float* cw_l   = cw   + (size_t)L * DINNER * DCONV;
        const float* cb_l   = cb   + (size_t)L * DINNER;
        const float* dpb_l  = dpb  + (size_t)L * DINNER;
        const float* alog_l = alog + (size_t)L * DINNER * DSTATE;
        const float* dpar_l = dpar + (size_t)L * DINNER;
        const unsigned short* wih_l = wih + (size_t)L * 2 * DINNER * DMODEL;
        const unsigned short* wil_l = wil + (size_t)L * 2 * DINNER * DMODEL;
        const unsigned short* woh_l = woh + (size_t)L * DMODEL * DINNER;
        const unsigned short* wol_l = wol + (size_t)L * DMODEL * DINNER;
        const unsigned short* wxh_l = wxh + (size_t)L * NPAD * DINNER;
        const unsigned short* wxl_l = wxl + (size_t)L * NPAD * DINNER;
        const unsigned short* wdh_l = wdh + (size_t)L * DINNER * KPAD;
        const unsigned short* wdl_l = wdl + (size_t)L * DINNER * KPAD;

        // GEMM1: xz[2048,3072] = A @ ipw^T   (512 blocks = 2/CU)
        gemm_pre<128, 96, 0><<<dim3(2 * DINNER / 96, MTOK / 128, 1), 256, 0, stream>>>(
            ah, al, DMODEL, wih_l, wil_l, DMODEL, xz, 2 * DINNER, DMODEL, 0, 1 << 30, nullptr);

        // conv + silu -> u (bf16 hi/lo)
        conv_silu_kernel<<<(MTOK * DINNER) / 256, 256, 0, stream>>>(xz, cw_l, cb_l, uh, ul);

        // GEMM2 (split-K=16): part[z][2048,80] = u-slice @ xpw-slice^T
        gemm_pre<64, 96, 0><<<dim3(1, MTOK / 64, KS2), 256, 0, stream>>>(
            uh, ul, DINNER, wxh_l, wxl_l, DINNER, part, XDIM,
            DINNER / KS2, (size_t)MTOK * XDIM, XDIM, nullptr);
        reduce16<<<(MTOK * XDIM / 4 + 255) / 256, 256, 0, stream>>>(part, xdbl, dth, dtl);

        // GEMM3: delta = softplus(dt @ dpw^T + dpb)   (K padded to 64)
        gemm_pre<128, 96, 2><<<dim3(DINNER / 96, MTOK / 128, 1), 256, 0, stream>>>(
            dth, dtl, KPAD, wdh_l, wdl_l, KPAD, delta, DINNER, KPAD, 0, 1 << 30, dpb_l);

        // chunked scan (3 passes), B/C rows in LDS; pass3 emits y bf16 hi/lo
        scan_pass1<<<dim3(DINNER / 256, NCHUNK, BATCH), 256, 0, stream>>>(
            delta, uh, ul, xdbl, alog_l, qbuf, sdlb);
        scan_pass2<<<CHSTRIDE / 256, 256, 0, stream>>>(qbuf, sdlb, alog_l, hinit);
        scan_pass3<<<dim3(DINNER / 256, NCHUNK, BATCH), 256, 0, stream>>>(
            delta, uh, ul, xdbl, xz, alog_l, dpar_l, hinit, yh, yl);

        // GEMM4 (split-K=4): part[z][2048,768] = y @ opw^T
        gemm_pre<128, 96, 0><<<dim3(DMODEL / 96, MTOK / 128, 4), 256, 0, stream>>>(
            yh, yl, DINNER, woh_l, wol_l, DINNER, part, DMODEL,
            DINNER / 4, (size_t)MTOK * DMODEL, 1 << 30, nullptr);

        // reduce split-K; L<3 -> next layer's A (bf16 hi/lo), L==3 -> fp32 out
        int rblocks = MTOK * DMODEL / 4 / 256;
        if (L == NL - 1) {
            reduce4<0><<<rblocks, 256, 0, stream>>>(part, out, nullptr, nullptr);
        } else {
            reduce4<1><<<rblocks, 256, 0, stream>>>(part, nullptr, ah, al);
        }
    }
    (void)in_sizes; (void)n_in; (void)out_size; (void)ws_size;
}

// Round 8
// 733.589 us; speedup vs baseline: 1.0565x; 1.0565x over previous
//
#include <hip/hip_runtime.h>
#include <math.h>

#define NL 4
#define DMODEL 768
#define DINNER 1536
#define DSTATE 16
#define DCONV 4
#define DTRANK 48
#define BATCH 2
#define SEQLEN 1024
#define MTOK (BATCH*SEQLEN)      // 2048
#define XDIM 80                  // DT_RANK + 2*D_STATE
#define KPAD 64                  // DTRANK padded for MFMA
#define NPAD 96                  // XDIM padded for MFMA (3x32)
#define KS2 16                   // split-K slices for GEMM2
#define NCHUNK 64
#define NCSHIFT 6
#define CLEN 16                  // SEQLEN/NCHUNK
#define CHSTRIDE (BATCH*16*DINNER)   // 49152

typedef __bf16 bf16x8 __attribute__((ext_vector_type(8)));
typedef float f32x4 __attribute__((ext_vector_type(4)));

__device__ __forceinline__ void splitbf(float f, unsigned short& hi, unsigned short& lo) {
    unsigned uh = __float_as_uint(f);
    unsigned rh = uh + (0x7fffu + ((uh >> 16) & 1u));
    unsigned short h = (unsigned short)(rh >> 16);
    float fh = __uint_as_float(((unsigned)h) << 16);
    float r = f - fh;
    unsigned ul = __float_as_uint(r);
    unsigned rl = ul + (0x7fffu + ((ul >> 16) & 1u));
    hi = h;
    lo = (unsigned short)(rl >> 16);
}

__device__ __forceinline__ void splitbf4(float4 v, ushort4& h, ushort4& l) {
    splitbf(v.x, h.x, l.x);
    splitbf(v.y, h.y, l.y);
    splitbf(v.z, h.z, l.z);
    splitbf(v.w, h.w, l.w);
}

__device__ __forceinline__ float bf2f(unsigned short h) {
    return __uint_as_float(((unsigned)h) << 16);
}

__device__ __forceinline__ void gload_lds16(const void* g, void* l) {
    __builtin_amdgcn_global_load_lds(
        (const __attribute__((address_space(1))) unsigned*)g,
        (__attribute__((address_space(3))) unsigned*)l, 16, 0, 0);
}

// ---------------------------------------------------------------------------
// One-shot prep for ALL layers: weight splits (+padding), dt pad-zero (L0),
// x split (L0). grid = (range, NL). Buffers hold all 4 layers.
// ---------------------------------------------------------------------------
#define N_IPW (2 * DINNER * DMODEL / 4)
#define N_OPW (DMODEL * DINNER / 4)
#define N_XPW (NPAD * DINNER / 4)
#define N_DPW (DINNER * KPAD / 4)
#define N_DTP (MTOK * (KPAD - DTRANK) / 4)
#define N_PREP (N_IPW + N_OPW + N_XPW + N_DPW + N_DTP)
#define N_XSPL (MTOK * DMODEL / 4)

__global__ __launch_bounds__(256) void prep_all(
    const float* __restrict__ ipw, const float* __restrict__ opw,
    const float* __restrict__ xpw, const float* __restrict__ dpw,
    const float* __restrict__ x,
    unsigned short* __restrict__ wih, unsigned short* __restrict__ wil,
    unsigned short* __restrict__ woh, unsigned short* __restrict__ wol,
    unsigned short* __restrict__ wxh, unsigned short* __restrict__ wxl,
    unsigned short* __restrict__ wdh, unsigned short* __restrict__ wdl,
    unsigned short* __restrict__ dth, unsigned short* __restrict__ dtl,
    unsigned short* __restrict__ ah, unsigned short* __restrict__ al)
{
    const int L = blockIdx.y;
    int i = blockIdx.x * 256 + threadIdx.x;
    if (i < N_IPW) {
        float4 v = ((const float4*)(ipw + (size_t)L * 2 * DINNER * DMODEL))[i];
        ushort4 h, l;
        splitbf4(v, h, l);
        size_t o = (size_t)L * N_IPW + i;
        ((ushort4*)wih)[o] = h;
        ((ushort4*)wil)[o] = l;
        return;
    }
    i -= N_IPW;
    if (i < N_OPW) {
        float4 v = ((const float4*)(opw + (size_t)L * DMODEL * DINNER))[i];
        ushort4 h, l;
        splitbf4(v, h, l);
        size_t o = (size_t)L * N_OPW + i;
        ((ushort4*)woh)[o] = h;
        ((ushort4*)wol)[o] = l;
        return;
    }
    i -= N_OPW;
    if (i < N_XPW) {
        int e = i * 4;
        int row = e / DINNER, col = e % DINNER;
        ushort4 h = {0, 0, 0, 0}, l = {0, 0, 0, 0};
        if (row < XDIM) {
            float4 v = *(const float4*)(xpw + (size_t)L * XDIM * DINNER + (size_t)row * DINNER + col);
            splitbf4(v, h, l);
        }
        size_t o = (size_t)L * N_XPW + i;
        ((ushort4*)wxh)[o] = h;
        ((ushort4*)wxl)[o] = l;
        return;
    }
    i -= N_XPW;
    if (i < N_DPW) {
        int e = i * 4;
        int row = e >> 6, col = e & 63;
        ushort4 h = {0, 0, 0, 0}, l = {0, 0, 0, 0};
        if (col < DTRANK) {
            float4 v = *(const float4*)(dpw + (size_t)L * DINNER * DTRANK + (size_t)row * DTRANK + col);
            splitbf4(v, h, l);
        }
        size_t o = (size_t)L * N_DPW + i;
        ((ushort4*)wdh)[o] = h;
        ((ushort4*)wdl)[o] = l;
        return;
    }
    i -= N_DPW;
    if (L != 0) return;                 // remaining ranges are layer-0 only
    if (i < N_DTP) {
        int e = i * 4;
        int row = e >> 4, col = DTRANK + (e & 15);
        int o = (row * KPAD + col) / 4;
        ushort4 z = {0, 0, 0, 0};
        ((ushort4*)dth)[o] = z;         // pad cols stay zero across all layers
        ((ushort4*)dtl)[o] = z;
        return;
    }
    i -= N_DTP;
    if (i < N_XSPL) {
        float4 v = ((const float4*)x)[i];
        ushort4 h, l;
        splitbf4(v, h, l);
        ((ushort4*)ah)[i] = h;
        ((ushort4*)al)[i] = l;
    }
}

// ---------------------------------------------------------------------------
// Pre-split 3-pass bf16 MFMA GEMM, XOR-swizzled LDS, 64x96 tile for occupancy
// (20 KB LDS, 4 blocks/CU at 1024-block grids).
// ---------------------------------------------------------------------------
template<int BM, int BN, int EPI>
__global__ __launch_bounds__(256, 4) void gemm_pre(
    const unsigned short* __restrict__ Ah, const unsigned short* __restrict__ Al, int lda,
    const unsigned short* __restrict__ Wh, const unsigned short* __restrict__ Wl, int ldw,
    float* __restrict__ C, int ldc, int Klen, size_t zstride, int nclip,
    const float* __restrict__ bias)
{
    constexpr int BK = 32;
    constexpr int MT = BM / 32, NT = BN / 32;
    constexpr int ACH = BM * 4;
    constexpr int WCH = BN * 4;
    __shared__ unsigned short sAh[BM * BK];
    __shared__ unsigned short sAl[BM * BK];
    __shared__ unsigned short sWh[BN * BK];
    __shared__ unsigned short sWl[BN * BK];

    const int tid = threadIdx.x;
    const int m0 = blockIdx.y * BM, n0 = blockIdx.x * BN;
    const int kbase = blockIdx.z * Klen;
    C += (size_t)blockIdx.z * zstride;
    const int lane = tid & 63, wave = tid >> 6;
    const int wr = wave >> 1, wc = wave & 1;
    const int wm0 = wr * (BM / 2), wn0 = wc * (BN / 2);
    const int lrow = lane & 15, lq = lane >> 4;

    f32x4 acc[MT][NT];
    #pragma unroll
    for (int mt = 0; mt < MT; mt++)
        #pragma unroll
        for (int nt = 0; nt < NT; nt++) {
            f32x4 z = {0.f, 0.f, 0.f, 0.f};
            acc[mt][nt] = z;
        }

    for (int k0 = kbase; k0 < kbase + Klen; k0 += BK) {
        #pragma unroll
        for (int i = 0; i < (ACH + 255) / 256; i++) {
            int chunk = i * 256 + tid;
            if (ACH % 256 == 0 || chunk < ACH) {
                int r = chunk >> 2, cp = chunk & 3;
                int c = cp ^ ((r >> 1) & 3);
                size_t goff = (size_t)(m0 + r) * lda + k0 + c * 8;
                gload_lds16(Ah + goff, &sAh[chunk * 8]);
                gload_lds16(Al + goff, &sAl[chunk * 8]);
            }
        }
        #pragma unroll
        for (int i = 0; i < (WCH + 255) / 256; i++) {
            int chunk = i * 256 + tid;
            if (WCH % 256 == 0 || chunk < WCH) {
                int r = chunk >> 2, cp = chunk & 3;
                int c = cp ^ ((r >> 1) & 3);
                size_t goff = (size_t)(n0 + r) * ldw + k0 + c * 8;
                gload_lds16(Wh + goff, &sWh[chunk * 8]);
                gload_lds16(Wl + goff, &sWl[chunk * 8]);
            }
        }
        __syncthreads();

        bf16x8 fah[MT], fal[MT], fwh[NT], fwl[NT];
        #pragma unroll
        for (int mt = 0; mt < MT; mt++) {
            int rr = wm0 + mt * 16 + lrow;
            int off = rr * BK + (lq ^ ((rr >> 1) & 3)) * 8;
            fah[mt] = *(const bf16x8*)&sAh[off];
            fal[mt] = *(const bf16x8*)&sAl[off];
        }
        #pragma unroll
        for (int nt = 0; nt < NT; nt++) {
            int rr = wn0 + nt * 16 + lrow;
            int off = rr * BK + (lq ^ ((rr >> 1) & 3)) * 8;
            fwh[nt] = *(const bf16x8*)&sWh[off];
            fwl[nt] = *(const bf16x8*)&sWl[off];
        }
        #pragma unroll
        for (int mt = 0; mt < MT; mt++)
            #pragma unroll
            for (int nt = 0; nt < NT; nt++) {
                acc[mt][nt] = __builtin_amdgcn_mfma_f32_16x16x32_bf16(fah[mt], fwh[nt], acc[mt][nt], 0, 0, 0);
                acc[mt][nt] = __builtin_amdgcn_mfma_f32_16x16x32_bf16(fah[mt], fwl[nt], acc[mt][nt], 0, 0, 0);
                acc[mt][nt] = __builtin_amdgcn_mfma_f32_16x16x32_bf16(fal[mt], fwh[nt], acc[mt][nt], 0, 0, 0);
            }
        __syncthreads();
    }

    // C/D layout: col = lane&15, row = (lane>>4)*4 + reg   [measured m89/m91]
    #pragma unroll
    for (int mt = 0; mt < MT; mt++)
        #pragma unroll
        for (int nt = 0; nt < NT; nt++)
            #pragma unroll
            for (int i = 0; i < 4; i++) {
                int row = m0 + wm0 + mt * 16 + lq * 4 + i;
                int col = n0 + wn0 + nt * 16 + lrow;
                float v = acc[mt][nt][i];
                if (EPI == 2) {
                    float t = v + bias[col];
                    v = fmaxf(t, 0.f) + log1pf(__expf(-fabsf(t)));
                }
                if (col < nclip) C[(size_t)row * ldc + col] = v;
            }
}

// ---------------------------------------------------------------------------
// split-K reduce (4 slices) + optional bf16 hi/lo split for next-layer A
// ---------------------------------------------------------------------------
template<int MODE>
__global__ __launch_bounds__(256) void reduce4(
    const float* __restrict__ part, float* __restrict__ dst,
    unsigned short* __restrict__ hi, unsigned short* __restrict__ lo)
{
    constexpr size_t S = (size_t)MTOK * DMODEL / 4;
    int i = blockIdx.x * 256 + threadIdx.x;
    const float4* p = (const float4*)part;
    float4 a = p[i], b = p[i + S], c = p[i + 2 * S], d = p[i + 3 * S];
    float4 s = {a.x + b.x + c.x + d.x, a.y + b.y + c.y + d.y,
                a.z + b.z + c.z + d.z, a.w + b.w + c.w + d.w};
    if (MODE == 0) {
        ((float4*)dst)[i] = s;
    } else {
        ushort4 h, l;
        splitbf4(s, h, l);
        ((ushort4*)hi)[i] = h;
        ((ushort4*)lo)[i] = l;
    }
}

// ---------------------------------------------------------------------------
// GEMM2 reduce: sum KS2 slices -> xdbl fp32; emit dt cols pre-split.
// ---------------------------------------------------------------------------
__global__ __launch_bounds__(256) void reduce16(
    const float* __restrict__ part, float* __restrict__ xdbl,
    unsigned short* __restrict__ dth, unsigned short* __restrict__ dtl)
{
    constexpr int N4 = MTOK * XDIM / 4;
    constexpr int S4 = MTOK * XDIM / 4;
    int i = blockIdx.x * 256 + threadIdx.x;
    if (i >= N4) return;
    const float4* p = (const float4*)part;
    float4 s = {0.f, 0.f, 0.f, 0.f};
    #pragma unroll
    for (int z = 0; z < KS2; z++) {
        float4 v = p[(size_t)z * S4 + i];
        s.x += v.x; s.y += v.y; s.z += v.z; s.w += v.w;
    }
    ((float4*)xdbl)[i] = s;
    int e = i * 4;
    int col = e % XDIM, row = e / XDIM;
    if (col < DTRANK) {
        ushort4 h, l;
        splitbf4(s, h, l);
        int o = (row * KPAD + col) / 4;
        ((ushort4*)dth)[o] = h;
        ((ushort4*)dtl)[o] = l;
    }
}

// ---------------------------------------------------------------------------
// causal depthwise conv (width 4) + silu -> u emitted as bf16 hi/lo
// ---------------------------------------------------------------------------
__global__ __launch_bounds__(256) void conv_silu_kernel(
    const float* __restrict__ xz, const float* __restrict__ cw,
    const float* __restrict__ cb,
    unsigned short* __restrict__ uh, unsigned short* __restrict__ ul)
{
    int idx = blockIdx.x * 256 + threadIdx.x;   // over MTOK*DINNER
    int d = idx % DINNER;
    int r = idx / DINNER;          // b*SEQLEN + l
    int l = r & (SEQLEN - 1);
    const float* base = xz + (size_t)r * (2 * DINNER) + d;
    float acc = cb[d];
    float w0 = cw[d * 4 + 0], w1 = cw[d * 4 + 1], w2 = cw[d * 4 + 2], w3 = cw[d * 4 + 3];
    if (l >= 3) acc = fmaf(w0, base[-3 * 2 * DINNER], acc);
    if (l >= 2) acc = fmaf(w1, base[-2 * 2 * DINNER], acc);
    if (l >= 1) acc = fmaf(w2, base[-1 * 2 * DINNER], acc);
    acc = fmaf(w3, base[0], acc);
    float uv = acc / (1.f + __expf(-acc));
    unsigned short h, lo_;
    splitbf(uv, h, lo_);
    uh[idx] = h;
    ul[idx] = lo_;
}

// ---------------------------------------------------------------------------
// Chunked parallel scan (3 passes), NCHUNK=64, flat grid (round-6 proven).
// pass1 emits q + sum(delta); pass2 reconstructs P = exp(Arow*sdl).
// ---------------------------------------------------------------------------
__global__ __launch_bounds__(256, 4) void scan_pass1(
    const float* __restrict__ delta,
    const unsigned short* __restrict__ uh, const unsigned short* __restrict__ ul,
    const float* __restrict__ xdbl, const float* __restrict__ A_log,
    float* __restrict__ qbuf, float* __restrict__ sdlbuf)
{
    int gid = blockIdx.x * 256 + threadIdx.x;  // BATCH*NCHUNK*DINNER
    int d = gid % DINNER;
    int r = gid / DINNER;
    int chunk = r & (NCHUNK - 1);
    int b = r >> NCSHIFT;
    float Arow[16], q[16];
    #pragma unroll
    for (int n = 0; n < 16; n++) {
        Arow[n] = -__expf(A_log[d * 16 + n]);
        q[n] = 0.f;
    }
    float sdl = 0.f;
    size_t rowbase = (size_t)b * SEQLEN * DINNER + d;
    int t0 = chunk * CLEN;
    #pragma unroll 2
    for (int i = 0; i < CLEN; i++) {
        int t = t0 + i;
        size_t o = rowbase + (size_t)t * DINNER;
        float dl = delta[o];
        float uu = bf2f(uh[o]) + bf2f(ul[o]);
        float du = dl * uu;
        sdl += dl;
        const float* Bp = xdbl + (size_t)(b * SEQLEN + t) * XDIM + DTRANK;
        #pragma unroll
        for (int n = 0; n < 16; n++) {
            float dA = __expf(dl * Arow[n]);
            q[n] = fmaf(dA, q[n], du * Bp[n]);
        }
    }
    size_t off = (size_t)((chunk * BATCH + b) * 16) * DINNER + d;
    #pragma unroll
    for (int n = 0; n < 16; n++)
        qbuf[off + (size_t)n * DINNER] = q[n];
    sdlbuf[(size_t)(chunk * BATCH + b) * DINNER + d] = sdl;
}

__global__ __launch_bounds__(256) void scan_pass2(
    const float* __restrict__ qbuf, const float* __restrict__ sdlbuf,
    const float* __restrict__ A_log, float* __restrict__ hinit)
{
    int gid = blockIdx.x * 256 + threadIdx.x;   // BATCH*16*DINNER
    int d = gid % DINNER;
    int n = (gid / DINNER) & 15;
    int b = gid / (16 * DINNER);
    float Arow = -__expf(A_log[d * 16 + n]);
    float h = 0.f;
    #pragma unroll 4
    for (int c = 0; c < NCHUNK; c++) {
        size_t o = (size_t)c * CHSTRIDE + gid;
        hinit[o] = h;
        float p = __expf(Arow * sdlbuf[(size_t)(c * BATCH + b) * DINNER + d]);
        h = fmaf(p, h, qbuf[o]);
    }
}

__global__ __launch_bounds__(256, 4) void scan_pass3(
    const float* __restrict__ delta,
    const unsigned short* __restrict__ uh, const unsigned short* __restrict__ ul,
    const float* __restrict__ xdbl, const float* __restrict__ xz,
    const float* __restrict__ A_log, const float* __restrict__ Dp,
    const float* __restrict__ hinit,
    unsigned short* __restrict__ yh, unsigned short* __restrict__ yl)
{
    int gid = blockIdx.x * 256 + threadIdx.x;
    int d = gid % DINNER;
    int r = gid / DINNER;
    int chunk = r & (NCHUNK - 1);
    int b = r >> NCSHIFT;
    float Arow[16], h[16];
    #pragma unroll
    for (int n = 0; n < 16; n++) Arow[n] = -__expf(A_log[d * 16 + n]);
    size_t hoff = (size_t)chunk * CHSTRIDE + (size_t)(b * 16) * DINNER + d;
    #pragma unroll
    for (int n = 0; n < 16; n++) h[n] = hinit[hoff + (size_t)n * DINNER];
    float Dpar = Dp[d];
    size_t rowbase = (size_t)b * SEQLEN * DINNER + d;
    int t0 = chunk * CLEN;
    #pragma unroll 2
    for (int i = 0; i < CLEN; i++) {
        int t = t0 + i;
        size_t o = rowbase + (size_t)t * DINNER;
        float dl = delta[o];
        float uu = bf2f(uh[o]) + bf2f(ul[o]);
        float du = dl * uu;
        const float* Bp = xdbl + (size_t)(b * SEQLEN + t) * XDIM + DTRANK;
        float yt = 0.f;
        #pragma unroll
        for (int n = 0; n < 16; n++) {
            float dA = __expf(dl * Arow[n]);
            h[n] = fmaf(dA, h[n], du * Bp[n]);
            yt = fmaf(h[n], Bp[16 + n], yt);
        }
        yt = fmaf(uu, Dpar, yt);
        float z = xz[(size_t)(b * SEQLEN + t) * (2 * DINNER) + DINNER + d];
        float sz = z / (1.f + __expf(-z));
        float yv = yt * sz;
        unsigned short hh, ll;
        splitbf(yv, hh, ll);
        yh[o] = hh;
        yl[o] = ll;
    }
}

// ---------------------------------------------------------------------------
extern "C" void kernel_launch(void* const* d_in, const int* in_sizes, int n_in,
                              void* d_out, int out_size, void* d_ws, size_t ws_size,
                              hipStream_t stream) {
    const float* x    = (const float*)d_in[0];
    const float* ipw  = (const float*)d_in[1];
    const float* cw   = (const float*)d_in[2];
    const float* cb   = (const float*)d_in[3];
    const float* xpw  = (const float*)d_in[4];
    const float* dpw  = (const float*)d_in[5];
    const float* dpb  = (const float*)d_in[6];
    const float* alog = (const float*)d_in[7];
    const float* dpar = (const float*)d_in[8];
    const float* opw  = (const float*)d_in[9];
    float* out = (float*)d_out;

    char* ws = (char*)d_ws;
    float* xz    = (float*)ws;            ws += (size_t)MTOK * 2 * DINNER * 4;
    float* delta = (float*)ws;            ws += (size_t)MTOK * DINNER * 4;
    float* xdbl  = (float*)ws;            ws += (size_t)MTOK * XDIM * 4;
    float* qbuf  = (float*)ws;            ws += (size_t)NCHUNK * CHSTRIDE * 4;
    float* hinit = (float*)ws;            ws += (size_t)NCHUNK * CHSTRIDE * 4;
    float* sdlb  = (float*)ws;            ws += (size_t)NCHUNK * BATCH * DINNER * 4;
    float* part  = (float*)ws;            ws += (size_t)4 * MTOK * DMODEL * 4;
    unsigned short* ah  = (unsigned short*)ws; ws += (size_t)MTOK * DMODEL * 2;
    unsigned short* al  = (unsigned short*)ws; ws += (size_t)MTOK * DMODEL * 2;
    unsigned short* yh  = (unsigned short*)ws; ws += (size_t)MTOK * DINNER * 2;
    unsigned short* yl  = (unsigned short*)ws; ws += (size_t)MTOK * DINNER * 2;
    unsigned short* uh  = (unsigned short*)ws; ws += (size_t)MTOK * DINNER * 2;
    unsigned short* ul  = (unsigned short*)ws; ws += (size_t)MTOK * DINNER * 2;
    unsigned short* wih = (unsigned short*)ws; ws += (size_t)NL * 2 * DINNER * DMODEL * 2;
    unsigned short* wil = (unsigned short*)ws; ws += (size_t)NL * 2 * DINNER * DMODEL * 2;
    unsigned short* woh = (unsigned short*)ws; ws += (size_t)NL * DMODEL * DINNER * 2;
    unsigned short* wol = (unsigned short*)ws; ws += (size_t)NL * DMODEL * DINNER * 2;
    unsigned short* wxh = (unsigned short*)ws; ws += (size_t)NL * NPAD * DINNER * 2;
    unsigned short* wxl = (unsigned short*)ws; ws += (size_t)NL * NPAD * DINNER * 2;
    unsigned short* wdh = (unsigned short*)ws; ws += (size_t)NL * DINNER * KPAD * 2;
    unsigned short* wdl = (unsigned short*)ws; ws += (size_t)NL * DINNER * KPAD * 2;
    unsigned short* dth = (unsigned short*)ws; ws += (size_t)MTOK * KPAD * 2;
    unsigned short* dtl = (unsigned short*)ws; ws += (size_t)MTOK * KPAD * 2;

    // one-shot prep: all 4 layers' weight splits + dt pad zero + x split
    prep_all<<<dim3((N_PREP + N_XSPL) / 256, NL), 256, 0, stream>>>(
        ipw, opw, xpw, dpw, x,
        wih, wil, woh, wol, wxh, wxl, wdh, wdl, dth, dtl, ah, al);

    for (int L = 0; L < NL; L++) {
        const float* cw_l   = cw   + (size_t)L * DINNER * DCONV;
        const float* cb_l   = cb   + (size_t)L * DINNER;
        const float* dpb_l  = dpb  + (size_t)L * DINNER;
        const float* alog_l = alog + (size_t)L * DINNER * DSTATE;
        const float* dpar_l = dpar + (size_t)L * DINNER;
        const unsigned short* wih_l = wih + (size_t)L * 2 * DINNER * DMODEL;
        const unsigned short* wil_l = wil + (size_t)L * 2 * DINNER * DMODEL;
        const unsigned short* woh_l = woh + (size_t)L * DMODEL * DINNER;
        const unsigned short* wol_l = wol + (size_t)L * DMODEL * DINNER;
        const unsigned short* wxh_l = wxh + (size_t)L * NPAD * DINNER;
        const unsigned short* wxl_l = wxl + (size_t)L * NPAD * DINNER;
        const unsigned short* wdh_l = wdh + (size_t)L * DINNER * KPAD;
        const unsigned short* wdl_l = wdl + (size_t)L * DINNER * KPAD;

        // GEMM1: xz[2048,3072] = A @ ipw^T   (1024 blocks = 4/CU)
        gemm_pre<64, 96, 0><<<dim3(2 * DINNER / 96, MTOK / 64, 1), 256, 0, stream>>>(
            ah, al, DMODEL, wih_l, wil_l, DMODEL, xz, 2 * DINNER, DMODEL, 0, 1 << 30, nullptr);

        // conv + silu -> u (bf16 hi/lo)
        conv_silu_kernel<<<(MTOK * DINNER) / 256, 256, 0, stream>>>(xz, cw_l, cb_l, uh, ul);

        // GEMM2 (split-K=16): part[z][2048,80] = u-slice @ xpw-slice^T
        gemm_pre<64, 96, 0><<<dim3(1, MTOK / 64, KS2), 256, 0, stream>>>(
            uh, ul, DINNER, wxh_l, wxl_l, DINNER, part, XDIM,
            DINNER / KS2, (size_t)MTOK * XDIM, XDIM, nullptr);
        reduce16<<<(MTOK * XDIM / 4 + 255) / 256, 256, 0, stream>>>(part, xdbl, dth, dtl);

        // GEMM3: delta = softplus(dt @ dpw^T + dpb)   (K padded to 64)
        gemm_pre<64, 96, 2><<<dim3(DINNER / 96, MTOK / 64, 1), 256, 0, stream>>>(
            dth, dtl, KPAD, wdh_l, wdl_l, KPAD, delta, DINNER, KPAD, 0, 1 << 30, dpb_l);

        // chunked scan (3 passes), flat grid; pass3 emits y bf16 hi/lo
        scan_pass1<<<(BATCH * NCHUNK * DINNER) / 256, 256, 0, stream>>>(
            delta, uh, ul, xdbl, alog_l, qbuf, sdlb);
        scan_pass2<<<CHSTRIDE / 256, 256, 0, stream>>>(qbuf, sdlb, alog_l, hinit);
        scan_pass3<<<(BATCH * NCHUNK * DINNER) / 256, 256, 0, stream>>>(
            delta, uh, ul, xdbl, xz, alog_l, dpar_l, hinit, yh, yl);

        // GEMM4 (split-K=4): part[z][2048,768] = y @ opw^T  (1024 blocks)
        gemm_pre<64, 96, 0><<<dim3(DMODEL / 96, MTOK / 64, 4), 256, 0, stream>>>(
            yh, yl, DINNER, woh_l, wol_l, DINNER, part, DMODEL,
            DINNER / 4, (size_t)MTOK * DMODEL, 1 << 30, nullptr);

        // reduce split-K; L<3 -> next layer's A (bf16 hi/lo), L==3 -> fp32 out
        int rblocks = MTOK * DMODEL / 4 / 256;
        if (L == NL - 1) {
            reduce4<0><<<rblocks, 256, 0, stream>>>(part, out, nullptr, nullptr);
        } else {
            reduce4<1><<<rblocks, 256, 0, stream>>>(part, nullptr, ah, al);
        }
    }
    (void)in_sizes; (void)n_in; (void)out_size; (void)ws_size;
}

// Round 9
// 724.887 us; speedup vs baseline: 1.0692x; 1.0120x over previous
//
#include <hip/hip_runtime.h>
#include <math.h>

#define NL 4
#define DMODEL 768
#define DINNER 1536
#define DSTATE 16
#define DCONV 4
#define DTRANK 48
#define BATCH 2
#define SEQLEN 1024
#define MTOK (BATCH*SEQLEN)      // 2048
#define XDIM 80                  // DT_RANK + 2*D_STATE
#define KPAD 64                  // DTRANK padded for MFMA
#define NPAD 96                  // XDIM padded for MFMA (3x32)
#define KS2 16                   // split-K slices for GEMM2
#define NCHUNK 64
#define NCSHIFT 6
#define CLEN 16                  // SEQLEN/NCHUNK
#define CHSTRIDE (BATCH*16*DINNER)   // 49152

typedef __bf16 bf16x8 __attribute__((ext_vector_type(8)));
typedef float f32x4 __attribute__((ext_vector_type(4)));

__device__ __forceinline__ void splitbf(float f, unsigned short& hi, unsigned short& lo) {
    unsigned uh = __float_as_uint(f);
    unsigned rh = uh + (0x7fffu + ((uh >> 16) & 1u));
    unsigned short h = (unsigned short)(rh >> 16);
    float fh = __uint_as_float(((unsigned)h) << 16);
    float r = f - fh;
    unsigned ul = __float_as_uint(r);
    unsigned rl = ul + (0x7fffu + ((ul >> 16) & 1u));
    hi = h;
    lo = (unsigned short)(rl >> 16);
}

__device__ __forceinline__ void splitbf4(float4 v, ushort4& h, ushort4& l) {
    splitbf(v.x, h.x, l.x);
    splitbf(v.y, h.y, l.y);
    splitbf(v.z, h.z, l.z);
    splitbf(v.w, h.w, l.w);
}

__device__ __forceinline__ float bf2f(unsigned short h) {
    return __uint_as_float(((unsigned)h) << 16);
}

__device__ __forceinline__ void gload_lds16(const void* g, void* l) {
    __builtin_amdgcn_global_load_lds(
        (const __attribute__((address_space(1))) unsigned*)g,
        (__attribute__((address_space(3))) unsigned*)l, 16, 0, 0);
}

// ---------------------------------------------------------------------------
// One-shot prep for ALL layers: weight splits (+padding), dt pad-zero (L0),
// x split (L0). grid = (range, NL). Buffers hold all 4 layers.
// ---------------------------------------------------------------------------
#define N_IPW (2 * DINNER * DMODEL / 4)
#define N_OPW (DMODEL * DINNER / 4)
#define N_XPW (NPAD * DINNER / 4)
#define N_DPW (DINNER * KPAD / 4)
#define N_DTP (MTOK * (KPAD - DTRANK) / 4)
#define N_PREP (N_IPW + N_OPW + N_XPW + N_DPW + N_DTP)
#define N_XSPL (MTOK * DMODEL / 4)

__global__ __launch_bounds__(256) void prep_all(
    const float* __restrict__ ipw, const float* __restrict__ opw,
    const float* __restrict__ xpw, const float* __restrict__ dpw,
    const float* __restrict__ x,
    unsigned short* __restrict__ wih, unsigned short* __restrict__ wil,
    unsigned short* __restrict__ woh, unsigned short* __restrict__ wol,
    unsigned short* __restrict__ wxh, unsigned short* __restrict__ wxl,
    unsigned short* __restrict__ wdh, unsigned short* __restrict__ wdl,
    unsigned short* __restrict__ dth, unsigned short* __restrict__ dtl,
    unsigned short* __restrict__ ah, unsigned short* __restrict__ al)
{
    const int L = blockIdx.y;
    int i = blockIdx.x * 256 + threadIdx.x;
    if (i < N_IPW) {
        float4 v = ((const float4*)(ipw + (size_t)L * 2 * DINNER * DMODEL))[i];
        ushort4 h, l;
        splitbf4(v, h, l);
        size_t o = (size_t)L * N_IPW + i;
        ((ushort4*)wih)[o] = h;
        ((ushort4*)wil)[o] = l;
        return;
    }
    i -= N_IPW;
    if (i < N_OPW) {
        float4 v = ((const float4*)(opw + (size_t)L * DMODEL * DINNER))[i];
        ushort4 h, l;
        splitbf4(v, h, l);
        size_t o = (size_t)L * N_OPW + i;
        ((ushort4*)woh)[o] = h;
        ((ushort4*)wol)[o] = l;
        return;
    }
    i -= N_OPW;
    if (i < N_XPW) {
        int e = i * 4;
        int row = e / DINNER, col = e % DINNER;
        ushort4 h = {0, 0, 0, 0}, l = {0, 0, 0, 0};
        if (row < XDIM) {
            float4 v = *(const float4*)(xpw + (size_t)L * XDIM * DINNER + (size_t)row * DINNER + col);
            splitbf4(v, h, l);
        }
        size_t o = (size_t)L * N_XPW + i;
        ((ushort4*)wxh)[o] = h;
        ((ushort4*)wxl)[o] = l;
        return;
    }
    i -= N_XPW;
    if (i < N_DPW) {
        int e = i * 4;
        int row = e >> 6, col = e & 63;
        ushort4 h = {0, 0, 0, 0}, l = {0, 0, 0, 0};
        if (col < DTRANK) {
            float4 v = *(const float4*)(dpw + (size_t)L * DINNER * DTRANK + (size_t)row * DTRANK + col);
            splitbf4(v, h, l);
        }
        size_t o = (size_t)L * N_DPW + i;
        ((ushort4*)wdh)[o] = h;
        ((ushort4*)wdl)[o] = l;
        return;
    }
    i -= N_DPW;
    if (L != 0) return;                 // remaining ranges are layer-0 only
    if (i < N_DTP) {
        int e = i * 4;
        int row = e >> 4, col = DTRANK + (e & 15);
        int o = (row * KPAD + col) / 4;
        ushort4 z = {0, 0, 0, 0};
        ((ushort4*)dth)[o] = z;         // pad cols stay zero across all layers
        ((ushort4*)dtl)[o] = z;
        return;
    }
    i -= N_DTP;
    if (i < N_XSPL) {
        float4 v = ((const float4*)x)[i];
        ushort4 h, l;
        splitbf4(v, h, l);
        ((ushort4*)ah)[i] = h;
        ((ushort4*)al)[i] = l;
    }
}

// ---------------------------------------------------------------------------
// Pre-split 3-pass bf16 MFMA GEMM, XOR-swizzled LDS (conflict-free, measured
// SQ_LDS_BANK_CONFLICT=0). 128x96 tile: 36 MFMA / 7 loads-per-thread per
// K-step — measured faster than 64x96 (40 vs 48.5 us) despite lower occupancy.
// ---------------------------------------------------------------------------
template<int BM, int BN, int EPI>
__global__ __launch_bounds__(256, (BM >= 128 ? 2 : 4)) void gemm_pre(
    const unsigned short* __restrict__ Ah, const unsigned short* __restrict__ Al, int lda,
    const unsigned short* __restrict__ Wh, const unsigned short* __restrict__ Wl, int ldw,
    float* __restrict__ C, int ldc, int Klen, size_t zstride, int nclip,
    const float* __restrict__ bias)
{
    constexpr int BK = 32;
    constexpr int MT = BM / 32, NT = BN / 32;
    constexpr int ACH = BM * 4;
    constexpr int WCH = BN * 4;
    __shared__ unsigned short sAh[BM * BK];
    __shared__ unsigned short sAl[BM * BK];
    __shared__ unsigned short sWh[BN * BK];
    __shared__ unsigned short sWl[BN * BK];

    const int tid = threadIdx.x;
    const int m0 = blockIdx.y * BM, n0 = blockIdx.x * BN;
    const int kbase = blockIdx.z * Klen;
    C += (size_t)blockIdx.z * zstride;
    const int lane = tid & 63, wave = tid >> 6;
    const int wr = wave >> 1, wc = wave & 1;
    const int wm0 = wr * (BM / 2), wn0 = wc * (BN / 2);
    const int lrow = lane & 15, lq = lane >> 4;

    f32x4 acc[MT][NT];
    #pragma unroll
    for (int mt = 0; mt < MT; mt++)
        #pragma unroll
        for (int nt = 0; nt < NT; nt++) {
            f32x4 z = {0.f, 0.f, 0.f, 0.f};
            acc[mt][nt] = z;
        }

    for (int k0 = kbase; k0 < kbase + Klen; k0 += BK) {
        #pragma unroll
        for (int i = 0; i < (ACH + 255) / 256; i++) {
            int chunk = i * 256 + tid;
            if (ACH % 256 == 0 || chunk < ACH) {
                int r = chunk >> 2, cp = chunk & 3;
                int c = cp ^ ((r >> 1) & 3);
                size_t goff = (size_t)(m0 + r) * lda + k0 + c * 8;
                gload_lds16(Ah + goff, &sAh[chunk * 8]);
                gload_lds16(Al + goff, &sAl[chunk * 8]);
            }
        }
        #pragma unroll
        for (int i = 0; i < (WCH + 255) / 256; i++) {
            int chunk = i * 256 + tid;
            if (WCH % 256 == 0 || chunk < WCH) {
                int r = chunk >> 2, cp = chunk & 3;
                int c = cp ^ ((r >> 1) & 3);
                size_t goff = (size_t)(n0 + r) * ldw + k0 + c * 8;
                gload_lds16(Wh + goff, &sWh[chunk * 8]);
                gload_lds16(Wl + goff, &sWl[chunk * 8]);
            }
        }
        __syncthreads();

        bf16x8 fah[MT], fal[MT], fwh[NT], fwl[NT];
        #pragma unroll
        for (int mt = 0; mt < MT; mt++) {
            int rr = wm0 + mt * 16 + lrow;
            int off = rr * BK + (lq ^ ((rr >> 1) & 3)) * 8;
            fah[mt] = *(const bf16x8*)&sAh[off];
            fal[mt] = *(const bf16x8*)&sAl[off];
        }
        #pragma unroll
        for (int nt = 0; nt < NT; nt++) {
            int rr = wn0 + nt * 16 + lrow;
            int off = rr * BK + (lq ^ ((rr >> 1) & 3)) * 8;
            fwh[nt] = *(const bf16x8*)&sWh[off];
            fwl[nt] = *(const bf16x8*)&sWl[off];
        }
        #pragma unroll
        for (int mt = 0; mt < MT; mt++)
            #pragma unroll
            for (int nt = 0; nt < NT; nt++) {
                acc[mt][nt] = __builtin_amdgcn_mfma_f32_16x16x32_bf16(fah[mt], fwh[nt], acc[mt][nt], 0, 0, 0);
                acc[mt][nt] = __builtin_amdgcn_mfma_f32_16x16x32_bf16(fah[mt], fwl[nt], acc[mt][nt], 0, 0, 0);
                acc[mt][nt] = __builtin_amdgcn_mfma_f32_16x16x32_bf16(fal[mt], fwh[nt], acc[mt][nt], 0, 0, 0);
            }
        __syncthreads();
    }

    // C/D layout: col = lane&15, row = (lane>>4)*4 + reg   [measured m89/m91]
    #pragma unroll
    for (int mt = 0; mt < MT; mt++)
        #pragma unroll
        for (int nt = 0; nt < NT; nt++)
            #pragma unroll
            for (int i = 0; i < 4; i++) {
                int row = m0 + wm0 + mt * 16 + lq * 4 + i;
                int col = n0 + wn0 + nt * 16 + lrow;
                float v = acc[mt][nt][i];
                if (EPI == 2) {
                    float t = v + bias[col];
                    v = fmaxf(t, 0.f) + log1pf(__expf(-fabsf(t)));
                }
                if (col < nclip) C[(size_t)row * ldc + col] = v;
            }
}

// ---------------------------------------------------------------------------
// split-K reduce (4 slices) + optional bf16 hi/lo split for next-layer A
// ---------------------------------------------------------------------------
template<int MODE>
__global__ __launch_bounds__(256) void reduce4(
    const float* __restrict__ part, float* __restrict__ dst,
    unsigned short* __restrict__ hi, unsigned short* __restrict__ lo)
{
    constexpr size_t S = (size_t)MTOK * DMODEL / 4;
    int i = blockIdx.x * 256 + threadIdx.x;
    const float4* p = (const float4*)part;
    float4 a = p[i], b = p[i + S], c = p[i + 2 * S], d = p[i + 3 * S];
    float4 s = {a.x + b.x + c.x + d.x, a.y + b.y + c.y + d.y,
                a.z + b.z + c.z + d.z, a.w + b.w + c.w + d.w};
    if (MODE == 0) {
        ((float4*)dst)[i] = s;
    } else {
        ushort4 h, l;
        splitbf4(s, h, l);
        ((ushort4*)hi)[i] = h;
        ((ushort4*)lo)[i] = l;
    }
}

// ---------------------------------------------------------------------------
// GEMM2 reduce: sum KS2 slices -> xdbl fp32; emit dt cols pre-split.
// ---------------------------------------------------------------------------
__global__ __launch_bounds__(256) void reduce16(
    const float* __restrict__ part, float* __restrict__ xdbl,
    unsigned short* __restrict__ dth, unsigned short* __restrict__ dtl)
{
    constexpr int N4 = MTOK * XDIM / 4;
    constexpr int S4 = MTOK * XDIM / 4;
    int i = blockIdx.x * 256 + threadIdx.x;
    if (i >= N4) return;
    const float4* p = (const float4*)part;
    float4 s = {0.f, 0.f, 0.f, 0.f};
    #pragma unroll
    for (int z = 0; z < KS2; z++) {
        float4 v = p[(size_t)z * S4 + i];
        s.x += v.x; s.y += v.y; s.z += v.z; s.w += v.w;
    }
    ((float4*)xdbl)[i] = s;
    int e = i * 4;
    int col = e % XDIM, row = e / XDIM;
    if (col < DTRANK) {
        ushort4 h, l;
        splitbf4(s, h, l);
        int o = (row * KPAD + col) / 4;
        ((ushort4*)dth)[o] = h;
        ((ushort4*)dtl)[o] = l;
    }
}

// ---------------------------------------------------------------------------
// causal depthwise conv (width 4) + silu -> u emitted as bf16 hi/lo
// ---------------------------------------------------------------------------
__global__ __launch_bounds__(256) void conv_silu_kernel(
    const float* __restrict__ xz, const float* __restrict__ cw,
    const float* __restrict__ cb,
    unsigned short* __restrict__ uh, unsigned short* __restrict__ ul)
{
    int idx = blockIdx.x * 256 + threadIdx.x;   // over MTOK*DINNER
    int d = idx % DINNER;
    int r = idx / DINNER;          // b*SEQLEN + l
    int l = r & (SEQLEN - 1);
    const float* base = xz + (size_t)r * (2 * DINNER) + d;
    float acc = cb[d];
    float w0 = cw[d * 4 + 0], w1 = cw[d * 4 + 1], w2 = cw[d * 4 + 2], w3 = cw[d * 4 + 3];
    if (l >= 3) acc = fmaf(w0, base[-3 * 2 * DINNER], acc);
    if (l >= 2) acc = fmaf(w1, base[-2 * 2 * DINNER], acc);
    if (l >= 1) acc = fmaf(w2, base[-1 * 2 * DINNER], acc);
    acc = fmaf(w3, base[0], acc);
    float uv = acc / (1.f + __expf(-acc));
    unsigned short h, lo_;
    splitbf(uv, h, lo_);
    uh[idx] = h;
    ul[idx] = lo_;
}

// ---------------------------------------------------------------------------
// Chunked parallel scan (3 passes), NCHUNK=64, flat grid.
// pass1 emits q + sum(delta); pass2 reconstructs P = exp(Arow*sdl).
// ---------------------------------------------------------------------------
__global__ __launch_bounds__(256, 4) void scan_pass1(
    const float* __restrict__ delta,
    const unsigned short* __restrict__ uh, const unsigned short* __restrict__ ul,
    const float* __restrict__ xdbl, const float* __restrict__ A_log,
    float* __restrict__ qbuf, float* __restrict__ sdlbuf)
{
    int gid = blockIdx.x * 256 + threadIdx.x;  // BATCH*NCHUNK*DINNER
    int d = gid % DINNER;
    int r = gid / DINNER;
    int chunk = r & (NCHUNK - 1);
    int b = r >> NCSHIFT;
    float Arow[16], q[16];
    #pragma unroll
    for (int n = 0; n < 16; n++) {
        Arow[n] = -__expf(A_log[d * 16 + n]);
        q[n] = 0.f;
    }
    float sdl = 0.f;
    size_t rowbase = (size_t)b * SEQLEN * DINNER + d;
    int t0 = chunk * CLEN;
    #pragma unroll 2
    for (int i = 0; i < CLEN; i++) {
        int t = t0 + i;
        size_t o = rowbase + (size_t)t * DINNER;
        float dl = delta[o];
        float uu = bf2f(uh[o]) + bf2f(ul[o]);
        float du = dl * uu;
        sdl += dl;
        const float* Bp = xdbl + (size_t)(b * SEQLEN + t) * XDIM + DTRANK;
        #pragma unroll
        for (int n = 0; n < 16; n++) {
            float dA = __expf(dl * Arow[n]);
            q[n] = fmaf(dA, q[n], du * Bp[n]);
        }
    }
    size_t off = (size_t)((chunk * BATCH + b) * 16) * DINNER + d;
    #pragma unroll
    for (int n = 0; n < 16; n++)
        qbuf[off + (size_t)n * DINNER] = q[n];
    sdlbuf[(size_t)(chunk * BATCH + b) * DINNER + d] = sdl;
}

__global__ __launch_bounds__(256) void scan_pass2(
    const float* __restrict__ qbuf, const float* __restrict__ sdlbuf,
    const float* __restrict__ A_log, float* __restrict__ hinit)
{
    int gid = blockIdx.x * 256 + threadIdx.x;   // BATCH*16*DINNER
    int d = gid % DINNER;
    int n = (gid / DINNER) & 15;
    int b = gid / (16 * DINNER);
    float Arow = -__expf(A_log[d * 16 + n]);
    float h = 0.f;
    #pragma unroll 4
    for (int c = 0; c < NCHUNK; c++) {
        size_t o = (size_t)c * CHSTRIDE + gid;
        hinit[o] = h;
        float p = __expf(Arow * sdlbuf[(size_t)(c * BATCH + b) * DINNER + d]);
        h = fmaf(p, h, qbuf[o]);
    }
}

__global__ __launch_bounds__(256, 4) void scan_pass3(
    const float* __restrict__ delta,
    const unsigned short* __restrict__ uh, const unsigned short* __restrict__ ul,
    const float* __restrict__ xdbl, const float* __restrict__ xz,
    const float* __restrict__ A_log, const float* __restrict__ Dp,
    const float* __restrict__ hinit,
    unsigned short* __restrict__ yh, unsigned short* __restrict__ yl)
{
    int gid = blockIdx.x * 256 + threadIdx.x;
    int d = gid % DINNER;
    int r = gid / DINNER;
    int chunk = r & (NCHUNK - 1);
    int b = r >> NCSHIFT;
    float Arow[16], h[16];
    #pragma unroll
    for (int n = 0; n < 16; n++) Arow[n] = -__expf(A_log[d * 16 + n]);
    size_t hoff = (size_t)chunk * CHSTRIDE + (size_t)(b * 16) * DINNER + d;
    #pragma unroll
    for (int n = 0; n < 16; n++) h[n] = hinit[hoff + (size_t)n * DINNER];
    float Dpar = Dp[d];
    size_t rowbase = (size_t)b * SEQLEN * DINNER + d;
    int t0 = chunk * CLEN;
    #pragma unroll 2
    for (int i = 0; i < CLEN; i++) {
        int t = t0 + i;
        size_t o = rowbase + (size_t)t * DINNER;
        float dl = delta[o];
        float uu = bf2f(uh[o]) + bf2f(ul[o]);
        float du = dl * uu;
        const float* Bp = xdbl + (size_t)(b * SEQLEN + t) * XDIM + DTRANK;
        float yt = 0.f;
        #pragma unroll
        for (int n = 0; n < 16; n++) {
            float dA = __expf(dl * Arow[n]);
            h[n] = fmaf(dA, h[n], du * Bp[n]);
            yt = fmaf(h[n], Bp[16 + n], yt);
        }
        yt = fmaf(uu, Dpar, yt);
        float z = xz[(size_t)(b * SEQLEN + t) * (2 * DINNER) + DINNER + d];
        float sz = z / (1.f + __expf(-z));
        float yv = yt * sz;
        unsigned short hh, ll;
        splitbf(yv, hh, ll);
        yh[o] = hh;
        yl[o] = ll;
    }
}

// ---------------------------------------------------------------------------
extern "C" void kernel_launch(void* const* d_in, const int* in_sizes, int n_in,
                              void* d_out, int out_size, void* d_ws, size_t ws_size,
                              hipStream_t stream) {
    const float* x    = (const float*)d_in[0];
    const float* ipw  = (const float*)d_in[1];
    const float* cw   = (const float*)d_in[2];
    const float* cb   = (const float*)d_in[3];
    const float* xpw  = (const float*)d_in[4];
    const float* dpw  = (const float*)d_in[5];
    const float* dpb  = (const float*)d_in[6];
    const float* alog = (const float*)d_in[7];
    const float* dpar = (const float*)d_in[8];
    const float* opw  = (const float*)d_in[9];
    float* out = (float*)d_out;

    char* ws = (char*)d_ws;
    float* xz    = (float*)ws;            ws += (size_t)MTOK * 2 * DINNER * 4;
    float* delta = (float*)ws;            ws += (size_t)MTOK * DINNER * 4;
    float* xdbl  = (float*)ws;            ws += (size_t)MTOK * XDIM * 4;
    float* qbuf  = (float*)ws;            ws += (size_t)NCHUNK * CHSTRIDE * 4;
    float* hinit = (float*)ws;            ws += (size_t)NCHUNK * CHSTRIDE * 4;
    float* sdlb  = (float*)ws;            ws += (size_t)NCHUNK * BATCH * DINNER * 4;
    float* part  = (float*)ws;            ws += (size_t)4 * MTOK * DMODEL * 4;
    unsigned short* ah  = (unsigned short*)ws; ws += (size_t)MTOK * DMODEL * 2;
    unsigned short* al  = (unsigned short*)ws; ws += (size_t)MTOK * DMODEL * 2;
    unsigned short* yh  = (unsigned short*)ws; ws += (size_t)MTOK * DINNER * 2;
    unsigned short* yl  = (unsigned short*)ws; ws += (size_t)MTOK * DINNER * 2;
    unsigned short* uh  = (unsigned short*)ws; ws += (size_t)MTOK * DINNER * 2;
    unsigned short* ul  = (unsigned short*)ws; ws += (size_t)MTOK * DINNER * 2;
    unsigned short* wih = (unsigned short*)ws; ws += (size_t)NL * 2 * DINNER * DMODEL * 2;
    unsigned short* wil = (unsigned short*)ws; ws += (size_t)NL * 2 * DINNER * DMODEL * 2;
    unsigned short* woh = (unsigned short*)ws; ws += (size_t)NL * DMODEL * DINNER * 2;
    unsigned short* wol = (unsigned short*)ws; ws += (size_t)NL * DMODEL * DINNER * 2;
    unsigned short* wxh = (unsigned short*)ws; ws += (size_t)NL * NPAD * DINNER * 2;
    unsigned short* wxl = (unsigned short*)ws; ws += (size_t)NL * NPAD * DINNER * 2;
    unsigned short* wdh = (unsigned short*)ws; ws += (size_t)NL * DINNER * KPAD * 2;
    unsigned short* wdl = (unsigned short*)ws; ws += (size_t)NL * DINNER * KPAD * 2;
    unsigned short* dth = (unsigned short*)ws; ws += (size_t)MTOK * KPAD * 2;
    unsigned short* dtl = (unsigned short*)ws; ws += (size_t)MTOK * KPAD * 2;

    // one-shot prep: all 4 layers' weight splits + dt pad zero + x split
    prep_all<<<dim3((N_PREP + N_XSPL) / 256, NL), 256, 0, stream>>>(
        ipw, opw, xpw, dpw, x,
        wih, wil, woh, wol, wxh, wxl, wdh, wdl, dth, dtl, ah, al);

    for (int L = 0; L < NL; L++) {
        const float* cw_l   = cw   + (size_t)L * DINNER * DCONV;
        const float* cb_l   = cb   + (size_t)L * DINNER;
        const float* dpb_l  = dpb  + (size_t)L * DINNER;
        const float* alog_l = alog + (size_t)L * DINNER * DSTATE;
        const float* dpar_l = dpar + (size_t)L * DINNER;
        const unsigned short* wih_l = wih + (size_t)L * 2 * DINNER * DMODEL;
        const unsigned short* wil_l = wil + (size_t)L * 2 * DINNER * DMODEL;
        const unsigned short* woh_l = woh + (size_t)L * DMODEL * DINNER;
        const unsigned short* wol_l = wol + (size_t)L * DMODEL * DINNER;
        const unsigned short* wxh_l = wxh + (size_t)L * NPAD * DINNER;
        const unsigned short* wxl_l = wxl + (size_t)L * NPAD * DINNER;
        const unsigned short* wdh_l = wdh + (size_t)L * DINNER * KPAD;
        const unsigned short* wdl_l = wdl + (size_t)L * DINNER * KPAD;

        // GEMM1: xz[2048,3072] = A @ ipw^T   (128x96, 512 blocks)
        gemm_pre<128, 96, 0><<<dim3(2 * DINNER / 96, MTOK / 128, 1), 256, 0, stream>>>(
            ah, al, DMODEL, wih_l, wil_l, DMODEL, xz, 2 * DINNER, DMODEL, 0, 1 << 30, nullptr);

        // conv + silu -> u (bf16 hi/lo)
        conv_silu_kernel<<<(MTOK * DINNER) / 256, 256, 0, stream>>>(xz, cw_l, cb_l, uh, ul);

        // GEMM2 (split-K=16): part[z][2048,80] = u-slice @ xpw-slice^T  (64x96)
        gemm_pre<64, 96, 0><<<dim3(1, MTOK / 64, KS2), 256, 0, stream>>>(
            uh, ul, DINNER, wxh_l, wxl_l, DINNER, part, XDIM,
            DINNER / KS2, (size_t)MTOK * XDIM, XDIM, nullptr);
        reduce16<<<(MTOK * XDIM / 4 + 255) / 256, 256, 0, stream>>>(part, xdbl, dth, dtl);

        // GEMM3: delta = softplus(dt @ dpw^T + dpb)   (128x96, K=64)
        gemm_pre<128, 96, 2><<<dim3(DINNER / 96, MTOK / 128, 1), 256, 0, stream>>>(
            dth, dtl, KPAD, wdh_l, wdl_l, KPAD, delta, DINNER, KPAD, 0, 1 << 30, dpb_l);

        // chunked scan (3 passes), flat grid; pass3 emits y bf16 hi/lo
        scan_pass1<<<(BATCH * NCHUNK * DINNER) / 256, 256, 0, stream>>>(
            delta, uh, ul, xdbl, alog_l, qbuf, sdlb);
        scan_pass2<<<CHSTRIDE / 256, 256, 0, stream>>>(qbuf, sdlb, alog_l, hinit);
        scan_pass3<<<(BATCH * NCHUNK * DINNER) / 256, 256, 0, stream>>>(
            delta, uh, ul, xdbl, xz, alog_l, dpar_l, hinit, yh, yl);

        // GEMM4 (split-K=4): part[z][2048,768] = y @ opw^T  (128x96, 512 blocks)
        gemm_pre<128, 96, 0><<<dim3(DMODEL / 96, MTOK / 128, 4), 256, 0, stream>>>(
            yh, yl, DINNER, woh_l, wol_l, DINNER, part, DMODEL,
            DINNER / 4, (size_t)MTOK * DMODEL, 1 << 30, nullptr);

        // reduce split-K; L<3 -> next layer's A (bf16 hi/lo), L==3 -> fp32 out
        int rblocks = MTOK * DMODEL / 4 / 256;
        if (L == NL - 1) {
            reduce4<0><<<rblocks, 256, 0, stream>>>(part, out, nullptr, nullptr);
        } else {
            reduce4<1><<<rblocks, 256, 0, stream>>>(part, nullptr, ah, al);
        }
    }
    (void)in_sizes; (void)n_in; (void)out_size; (void)ws_size;
}